// Round 1
// baseline (893.647 us; speedup 1.0000x reference)
//
#include <hip/hip_runtime.h>

// One thread per optimizee parameter (row). Weights staged in LDS (broadcast
// reads). Dynamic 20-iteration gate loops keep I$ footprint small; h-state
// round-trips through a padded LDS tile so it re-enters registers with static
// indices for the unrolled dot products and vectorized stores.

#define BLK 256

__device__ __forceinline__ float rcp_(float x) { return __builtin_amdgcn_rcpf(x); }
__device__ __forceinline__ float sig_(float x) { return rcp_(1.0f + __expf(-x)); }
__device__ __forceinline__ float th_(float x)  { return 1.0f - 2.0f * rcp_(__expf(2.0f * x) + 1.0f); }

// LDS weight layout (floats):
//  [0,160)      Wih1 [80,2]
//  [160,1760)   Whh1 [80,20]
//  [1760,3360)  Wih2 [80,20]
//  [3360,4960)  Whh2 [80,20]
//  [4960,5040)  b1 = bih1+bhh1
//  [5040,5120)  b2 = bih2+bhh2
//  [5120,5140)  Wout
//  [5140]       bout

__global__ __launch_bounds__(BLK) void opt_lstm_kernel(
    const float* __restrict__ inp,
    const float* __restrict__ h0, const float* __restrict__ h1,
    const float* __restrict__ c0, const float* __restrict__ c1,
    const float* __restrict__ Wih1, const float* __restrict__ Whh1,
    const float* __restrict__ bih1, const float* __restrict__ bhh1,
    const float* __restrict__ Wih2, const float* __restrict__ Whh2,
    const float* __restrict__ bih2, const float* __restrict__ bhh2,
    const float* __restrict__ Wout, const float* __restrict__ bout,
    float* __restrict__ outO, float* __restrict__ outH0, float* __restrict__ outH1,
    float* __restrict__ outC0, float* __restrict__ outC1, int Ntot)
{
    __shared__ __align__(16) float sW[5144];
    __shared__ __align__(16) float ht[BLK * 21];   // stride 21: coprime w/ 32 banks

    const int tid = threadIdx.x;
    for (int i = tid; i < 160; i += BLK) sW[i] = Wih1[i];
    for (int i = tid; i < 1600; i += BLK) {
        sW[160 + i]  = Whh1[i];
        sW[1760 + i] = Wih2[i];
        sW[3360 + i] = Whh2[i];
    }
    if (tid < 80) {
        sW[4960 + tid] = bih1[tid] + bhh1[tid];
        sW[5040 + tid] = bih2[tid] + bhh2[tid];
    }
    if (tid < 20) sW[5120 + tid] = Wout[tid];
    if (tid == 0) sW[5140] = bout[0];
    __syncthreads();   // no barriers after this point -> early-exit is safe

    const int n = blockIdx.x * BLK + tid;
    if (n >= Ntot) return;

    // ---- preprocess (stop_gradient irrelevant for forward) ----
    float x  = inp[n];
    float ax = fabsf(x);
    bool keep = ax >= 4.5399930e-05f;            // exp(-10) as f32
    float a = keep ? (__logf(ax + 1e-8f) * 0.1f) : -1.0f;
    float b = keep ? ((x > 0.0f) ? 1.0f : -1.0f) : 22026.4658f * x;  // exp(10)*x

    const int rowb = n * 20;

    float h0r[20];
    {
        const float4* p = (const float4*)(h0 + (size_t)rowb);
#pragma unroll
        for (int q = 0; q < 5; ++q) {
            float4 v = p[q];
            h0r[4*q] = v.x; h0r[4*q+1] = v.y; h0r[4*q+2] = v.z; h0r[4*q+3] = v.w;
        }
    }

    // ---- LSTM cell 1 ----
    for (int k = 0; k < 20; ++k) {
        float cprev = c0[rowb + k];
        float gi = sW[4960 + k]      + sW[2*k]        * a + sW[2*k + 1]        * b;
        float gf = sW[4960 + 20 + k] + sW[2*(k+20)]   * a + sW[2*(k+20) + 1]   * b;
        float gg = sW[4960 + 40 + k] + sW[2*(k+40)]   * a + sW[2*(k+40) + 1]   * b;
        float go = sW[4960 + 60 + k] + sW[2*(k+60)]   * a + sW[2*(k+60) + 1]   * b;
        const float4* wi = (const float4*)&sW[160 + 20*k];
        const float4* wf = (const float4*)&sW[160 + 20*(k+20)];
        const float4* wg = (const float4*)&sW[160 + 20*(k+40)];
        const float4* wo = (const float4*)&sW[160 + 20*(k+60)];
#pragma unroll
        for (int q = 0; q < 5; ++q) {
            float4 vi = wi[q], vf = wf[q], vg = wg[q], vo = wo[q];
            float ha = h0r[4*q], hb = h0r[4*q+1], hc = h0r[4*q+2], hd = h0r[4*q+3];
            gi += vi.x*ha + vi.y*hb + vi.z*hc + vi.w*hd;
            gf += vf.x*ha + vf.y*hb + vf.z*hc + vf.w*hd;
            gg += vg.x*ha + vg.y*hb + vg.z*hc + vg.w*hd;
            go += vo.x*ha + vo.y*hb + vo.z*hc + vo.w*hd;
        }
        float iv = sig_(gi), fv = sig_(gf), gv = th_(gg), ov = sig_(go);
        float cn = fv * cprev + iv * gv;
        float hn = ov * th_(cn);
        outC0[rowb + k] = cn;
        ht[tid * 21 + k] = hn;
    }

    float h0nr[20];
#pragma unroll
    for (int m = 0; m < 20; ++m) h0nr[m] = ht[tid * 21 + m];
    {
        float4* p = (float4*)(outH0 + (size_t)rowb);
#pragma unroll
        for (int q = 0; q < 5; ++q)
            p[q] = make_float4(h0nr[4*q], h0nr[4*q+1], h0nr[4*q+2], h0nr[4*q+3]);
    }

    float h1r[20];
    {
        const float4* p = (const float4*)(h1 + (size_t)rowb);
#pragma unroll
        for (int q = 0; q < 5; ++q) {
            float4 v = p[q];
            h1r[4*q] = v.x; h1r[4*q+1] = v.y; h1r[4*q+2] = v.z; h1r[4*q+3] = v.w;
        }
    }

    // ---- LSTM cell 2 ----
    for (int k = 0; k < 20; ++k) {
        float cprev = c1[rowb + k];
        float gi = sW[5040 + k];
        float gf = sW[5040 + 20 + k];
        float gg = sW[5040 + 40 + k];
        float go = sW[5040 + 60 + k];
        const float4* ai = (const float4*)&sW[1760 + 20*k];
        const float4* af = (const float4*)&sW[1760 + 20*(k+20)];
        const float4* ag = (const float4*)&sW[1760 + 20*(k+40)];
        const float4* ao = (const float4*)&sW[1760 + 20*(k+60)];
        const float4* bi = (const float4*)&sW[3360 + 20*k];
        const float4* bf = (const float4*)&sW[3360 + 20*(k+20)];
        const float4* bg = (const float4*)&sW[3360 + 20*(k+40)];
        const float4* bo = (const float4*)&sW[3360 + 20*(k+60)];
#pragma unroll
        for (int q = 0; q < 5; ++q) {
            float4 va = ai[q], vb = af[q], vc = ag[q], vd = ao[q];
            float xa = h0nr[4*q], xb = h0nr[4*q+1], xc = h0nr[4*q+2], xd = h0nr[4*q+3];
            gi += va.x*xa + va.y*xb + va.z*xc + va.w*xd;
            gf += vb.x*xa + vb.y*xb + vb.z*xc + vb.w*xd;
            gg += vc.x*xa + vc.y*xb + vc.z*xc + vc.w*xd;
            go += vd.x*xa + vd.y*xb + vd.z*xc + vd.w*xd;
            float4 wa = bi[q], wb = bf[q], wc = bg[q], wd = bo[q];
            float ya = h1r[4*q], yb = h1r[4*q+1], yc = h1r[4*q+2], yd = h1r[4*q+3];
            gi += wa.x*ya + wa.y*yb + wa.z*yc + wa.w*yd;
            gf += wb.x*ya + wb.y*yb + wb.z*yc + wb.w*yd;
            gg += wc.x*ya + wc.y*yb + wc.z*yc + wc.w*yd;
            go += wd.x*ya + wd.y*yb + wd.z*yc + wd.w*yd;
        }
        float iv = sig_(gi), fv = sig_(gf), gv = th_(gg), ov = sig_(go);
        float cn = fv * cprev + iv * gv;
        float hn = ov * th_(cn);
        outC1[rowb + k] = cn;
        ht[tid * 21 + k] = hn;
    }

    float h1nr[20];
#pragma unroll
    for (int m = 0; m < 20; ++m) h1nr[m] = ht[tid * 21 + m];

    float acc = sW[5140];
#pragma unroll
    for (int m = 0; m < 20; ++m) acc += sW[5120 + m] * h1nr[m];

    {
        float4* p = (float4*)(outH1 + (size_t)rowb);
#pragma unroll
        for (int q = 0; q < 5; ++q)
            p[q] = make_float4(h1nr[4*q], h1nr[4*q+1], h1nr[4*q+2], h1nr[4*q+3]);
    }
    outO[n] = acc;
}

extern "C" void kernel_launch(void* const* d_in, const int* in_sizes, int n_in,
                              void* d_out, int out_size, void* d_ws, size_t ws_size,
                              hipStream_t stream) {
    const float* inp  = (const float*)d_in[0];
    const float* h0   = (const float*)d_in[1];
    const float* h1   = (const float*)d_in[2];
    const float* c0   = (const float*)d_in[3];
    const float* c1   = (const float*)d_in[4];
    const float* Wih1 = (const float*)d_in[5];
    const float* Whh1 = (const float*)d_in[6];
    const float* bih1 = (const float*)d_in[7];
    const float* bhh1 = (const float*)d_in[8];
    const float* Wih2 = (const float*)d_in[9];
    const float* Whh2 = (const float*)d_in[10];
    const float* bih2 = (const float*)d_in[11];
    const float* bhh2 = (const float*)d_in[12];
    const float* Wout = (const float*)d_in[13];
    const float* bout = (const float*)d_in[14];

    const int N = in_sizes[0];           // inp is [N,1]
    float* out = (float*)d_out;          // (out, h0n, h1n, c0n, c1n) flat
    float* oO  = out;
    float* oH0 = out + (size_t)N;
    float* oH1 = out + (size_t)21 * N;
    float* oC0 = out + (size_t)41 * N;
    float* oC1 = out + (size_t)61 * N;

    const int grid = (N + BLK - 1) / BLK;
    hipLaunchKernelGGL(opt_lstm_kernel, dim3(grid), dim3(BLK), 0, stream,
                       inp, h0, h1, c0, c1,
                       Wih1, Whh1, bih1, bhh1,
                       Wih2, Whh2, bih2, bhh2,
                       Wout, bout,
                       oO, oH0, oH1, oC0, oC1, N);
}